// Round 1
// baseline (1152.941 us; speedup 1.0000x reference)
//
#include <hip/hip_runtime.h>
#include <math.h>

#define NPG 256
#define NB 1024
#define NN (NB * NPG)          // 262144 nodes
#define HID 192
#define HID2 384
#define NE 4194304
#define KTOP 231
#define LNEPS 1e-5f

#define ROWS 64                // rows (nodes) per block
#define KB 8                   // k-slab for W1 staging
#define XPAD 196               // 192+4: keeps 16B alignment, breaks 192%32 banking

// ---------------------------------------------------------------------------
// Kernel A: fused logits = Linear(192->384) -> LayerNorm -> ReLU -> Linear(384->1)
// One block: 64 rows x 384 cols, K=192. Thread tile: 4 rows x 24 cols.
// cols per thread are interleaved: col(m,q) = m*64 + cg*4 + q  (2-way LDS banking)
// ---------------------------------------------------------------------------
__global__ __launch_bounds__(256) void logits_kernel(
    const float* __restrict__ h, const float* __restrict__ g,
    const float* __restrict__ W1, const float* __restrict__ b1,
    const float* __restrict__ gamma, const float* __restrict__ beta,
    const float* __restrict__ W2, const float* __restrict__ b2,
    float* __restrict__ logits_out)
{
    __shared__ float Xs[ROWS * XPAD];   // 64*196*4 = 50176 B
    __shared__ float Ws[KB * HID2];     // 8*384*4  = 12288 B  (total 62464 <= 64K)

    const int tid = threadIdx.x;
    const int blk = blockIdx.x;
    const int row0 = blk * ROWS;        // 64 | 256 -> whole block in one graph
    const int graph = row0 / NPG;

    // stage X = h + g_rep  (64 rows x 192 cols = 3072 float4, 12 per thread)
    {
        const float4* h4 = (const float4*)(h + (size_t)row0 * HID);
        const float4* g4 = (const float4*)(g + (size_t)graph * HID);
        #pragma unroll
        for (int it = 0; it < 12; ++it) {
            int f = tid + it * 256;
            int r = f / 48, c = f - r * 48;        // c in float4 units
            float4 hv = h4[r * 48 + c];
            float4 gv = g4[c];
            float4 xv = make_float4(hv.x + gv.x, hv.y + gv.y, hv.z + gv.z, hv.w + gv.w);
            *(float4*)(&Xs[r * XPAD + c * 4]) = xv;
        }
    }

    const int cg = tid & 15;    // column group 0..15
    const int rg = tid >> 4;    // row group 0..15
    const int r0 = rg * 4;

    float acc[4][24];
    #pragma unroll
    for (int i = 0; i < 4; ++i)
        #pragma unroll
        for (int j = 0; j < 24; ++j) acc[i][j] = 0.f;

    for (int ks = 0; ks < HID; ks += KB) {
        __syncthreads();
        {   // stage W1 slab: 8x384 floats = 768 float4, 3 per thread
            const float4* w4 = (const float4*)(W1 + (size_t)ks * HID2);
            float4* s4 = (float4*)Ws;
            #pragma unroll
            for (int it = 0; it < 3; ++it) s4[tid + it * 256] = w4[tid + it * 256];
        }
        __syncthreads();
        #pragma unroll
        for (int kk = 0; kk < KB; ++kk) {
            float a[4];
            #pragma unroll
            for (int i = 0; i < 4; ++i) a[i] = Xs[(r0 + i) * XPAD + ks + kk];
            float4 bv[6];
            const float* wrow = &Ws[kk * HID2];
            #pragma unroll
            for (int m = 0; m < 6; ++m) bv[m] = *(const float4*)(&wrow[m * 64 + cg * 4]);
            #pragma unroll
            for (int i = 0; i < 4; ++i) {
                #pragma unroll
                for (int m = 0; m < 6; ++m) {
                    acc[i][m*4+0] = fmaf(a[i], bv[m].x, acc[i][m*4+0]);
                    acc[i][m*4+1] = fmaf(a[i], bv[m].y, acc[i][m*4+1]);
                    acc[i][m*4+2] = fmaf(a[i], bv[m].z, acc[i][m*4+2]);
                    acc[i][m*4+3] = fmaf(a[i], bv[m].w, acc[i][m*4+3]);
                }
            }
        }
    }

    // epilogue: +b1, LayerNorm over 384 (own 24 + shfl over the 16 col-groups),
    // ReLU, dot with W2, +b2
    float4 b1v[6], gav[6], bev[6], w2v[6];
    #pragma unroll
    for (int m = 0; m < 6; ++m) {
        int c0 = m * 64 + cg * 4;
        b1v[m] = *(const float4*)(&b1[c0]);
        gav[m] = *(const float4*)(&gamma[c0]);
        bev[m] = *(const float4*)(&beta[c0]);
        w2v[m] = *(const float4*)(&W2[c0]);
    }
    const float b2v = b2[0];

    #pragma unroll
    for (int i = 0; i < 4; ++i) {
        #pragma unroll
        for (int m = 0; m < 6; ++m) {
            acc[i][m*4+0] += b1v[m].x;
            acc[i][m*4+1] += b1v[m].y;
            acc[i][m*4+2] += b1v[m].z;
            acc[i][m*4+3] += b1v[m].w;
        }
    }

    #pragma unroll
    for (int i = 0; i < 4; ++i) {
        float s = 0.f, s2 = 0.f;
        #pragma unroll
        for (int j = 0; j < 24; ++j) { float v = acc[i][j]; s += v; s2 += v * v; }
        #pragma unroll
        for (int off = 1; off < 16; off <<= 1) {
            s  += __shfl_xor(s,  off);
            s2 += __shfl_xor(s2, off);
        }
        float mu  = s  * (1.f / HID2);
        float var = s2 * (1.f / HID2) - mu * mu;
        float rs  = rsqrtf(var + LNEPS);
        float lg = 0.f;
        #pragma unroll
        for (int m = 0; m < 6; ++m) {
            float zn;
            zn = (acc[i][m*4+0] - mu) * rs * gav[m].x + bev[m].x; zn = fmaxf(zn, 0.f); lg = fmaf(zn, w2v[m].x, lg);
            zn = (acc[i][m*4+1] - mu) * rs * gav[m].y + bev[m].y; zn = fmaxf(zn, 0.f); lg = fmaf(zn, w2v[m].y, lg);
            zn = (acc[i][m*4+2] - mu) * rs * gav[m].z + bev[m].z; zn = fmaxf(zn, 0.f); lg = fmaf(zn, w2v[m].z, lg);
            zn = (acc[i][m*4+3] - mu) * rs * gav[m].w + bev[m].w; zn = fmaxf(zn, 0.f); lg = fmaf(zn, w2v[m].w, lg);
        }
        #pragma unroll
        for (int off = 1; off < 16; off <<= 1) lg += __shfl_xor(lg, off);
        if (cg == 0) logits_out[row0 + r0 + i] = lg + b2v;
    }
}

// ---------------------------------------------------------------------------
// Kernel B: per-graph top-K keep mask via rank counting (stable, matches
// jax.lax.top_k tie-breaking: ties broken by lower index). Also zeroes touched.
// ---------------------------------------------------------------------------
__global__ __launch_bounds__(256) void topk_kernel(
    const float* __restrict__ logits, float* __restrict__ keep,
    int* __restrict__ touched)
{
    __shared__ float arr[NPG];
    const int tid = threadIdx.x;
    const int n = blockIdx.x * NPG + tid;
    float v = logits[n];
    arr[tid] = v;
    touched[n] = 0;
    __syncthreads();
    int rank = 0;
    #pragma unroll 16
    for (int j = 0; j < NPG; ++j) {
        float a = arr[j];
        rank += (a > v || (a == v && j < tid)) ? 1 : 0;
    }
    keep[n] = (rank < KTOP) ? 1.0f : 0.0f;
}

// ---------------------------------------------------------------------------
// Kernel C: edge mask + edge weight + touched accumulation
// ---------------------------------------------------------------------------
__global__ __launch_bounds__(256) void edge_kernel(
    const int* __restrict__ ei, const float* __restrict__ logits,
    const float* __restrict__ keep, float* __restrict__ mask_out,
    float* __restrict__ w_out, int* __restrict__ touched)
{
    const int e = blockIdx.x * blockDim.x + threadIdx.x;
    const int s = ei[e];
    const int d = ei[NE + e];
    const float m = keep[s] * keep[d];
    mask_out[e] = m;
    w_out[e] = (logits[s] + logits[d]) * m;
    if (m != 0.f) {
        atomicOr(&touched[s], 1);
        atomicOr(&touched[d], 1);
    }
}

// ---------------------------------------------------------------------------
// Kernel D: node mask from touched
// ---------------------------------------------------------------------------
__global__ __launch_bounds__(256) void nodemask_kernel(
    const int* __restrict__ touched, float* __restrict__ nm)
{
    const int n = blockIdx.x * blockDim.x + threadIdx.x;
    nm[n] = touched[n] ? 1.0f : 0.0f;
}

extern "C" void kernel_launch(void* const* d_in, const int* in_sizes, int n_in,
                              void* d_out, int out_size, void* d_ws, size_t ws_size,
                              hipStream_t stream)
{
    const float* h     = (const float*)d_in[0];
    const float* g     = (const float*)d_in[1];
    const int*   ei    = (const int*)d_in[2];
    const float* W1    = (const float*)d_in[3];
    const float* b1    = (const float*)d_in[4];
    const float* gamma = (const float*)d_in[5];
    const float* beta  = (const float*)d_in[6];
    const float* W2    = (const float*)d_in[7];
    const float* b2    = (const float*)d_in[8];

    float* out        = (float*)d_out;
    float* out_mask   = out;                       // [E]
    float* out_w      = out + (size_t)NE;          // [E]
    float* out_logits = out + 2 * (size_t)NE;      // [N]
    float* out_nm     = out_logits + (size_t)NN;   // [N]

    float* keep    = (float*)d_ws;                         // N floats
    int*   touched = (int*)((char*)d_ws + (size_t)NN * 4); // N ints

    hipLaunchKernelGGL(logits_kernel, dim3(NN / ROWS), dim3(256), 0, stream,
                       h, g, W1, b1, gamma, beta, W2, b2, out_logits);
    hipLaunchKernelGGL(topk_kernel, dim3(NB), dim3(256), 0, stream,
                       out_logits, keep, touched);
    hipLaunchKernelGGL(edge_kernel, dim3(NE / 256), dim3(256), 0, stream,
                       ei, out_logits, keep, out_mask, out_w, touched);
    hipLaunchKernelGGL(nodemask_kernel, dim3(NN / 256), dim3(256), 0, stream,
                       touched, out_nm);
}

// Round 2
// 968.941 us; speedup vs baseline: 1.1899x; 1.1899x over previous
//
#include <hip/hip_runtime.h>
#include <math.h>

#define NPG 256
#define NB 1024
#define NN (NB * NPG)          // 262144 nodes
#define HID 192
#define HID2 384
#define NE 4194304
#define KTOP 231
#define LNEPS 1e-5f

#define ROWS 64                // rows (nodes) per block
#define KB 4                   // k-slab for W1 double-buffered staging
#define NSLAB (HID / KB)       // 48
#define XPAD 196               // 192+4: keeps 16B alignment

// ---------------------------------------------------------------------------
// Kernel A: fused logits = Linear(192->384) -> LayerNorm -> ReLU -> Linear(384->1)
// One block: 64 rows x 384 cols, K=192. Thread tile: 4 rows x 24 cols.
// W1 staged in KB=4 k-slabs, DOUBLE-BUFFERED in LDS with register prefetch:
// one barrier per slab; global-load latency hidden behind the slab's FMAs.
// ---------------------------------------------------------------------------
__global__ __launch_bounds__(256) void logits_kernel(
    const float* __restrict__ h, const float* __restrict__ g,
    const float* __restrict__ W1, const float* __restrict__ b1,
    const float* __restrict__ gamma, const float* __restrict__ beta,
    const float* __restrict__ W2, const float* __restrict__ b2,
    float* __restrict__ logits_out)
{
    __shared__ float Xs[ROWS * XPAD];       // 64*196*4 = 50176 B
    __shared__ float Ws[2][KB * HID2];      // 2*4*384*4 = 12288 B (tot 62464)

    const int tid = threadIdx.x;
    const int blk = blockIdx.x;
    const int row0 = blk * ROWS;            // 64 | 256 -> block within one graph
    const int graph = row0 / NPG;

    // stage X = h + g_rep  (64 rows x 192 cols = 3072 float4, 12 per thread)
    {
        const float4* h4 = (const float4*)(h + (size_t)row0 * HID);
        const float4* g4 = (const float4*)(g + (size_t)graph * HID);
        #pragma unroll
        for (int it = 0; it < 12; ++it) {
            int f = tid + it * 256;
            int r = f / 48, c = f - r * 48;        // c in float4 units
            float4 hv = h4[r * 48 + c];
            float4 gv = g4[c];
            float4 xv = make_float4(hv.x + gv.x, hv.y + gv.y, hv.z + gv.z, hv.w + gv.w);
            *(float4*)(&Xs[r * XPAD + c * 4]) = xv;
        }
    }

    // prologue: slab 0 -> registers -> Ws[0]
    const float2* w1v = (const float2*)W1;  // slab s = 768 float2 at s*768
    {
        float2 wreg[3];
        #pragma unroll
        for (int j = 0; j < 3; ++j) wreg[j] = w1v[tid + j * 256];
        float2* dst = (float2*)Ws[0];
        #pragma unroll
        for (int j = 0; j < 3; ++j) dst[tid + j * 256] = wreg[j];
    }

    const int cg = tid & 15;    // column group 0..15
    const int rg = tid >> 4;    // row group 0..15
    const int r0 = rg * 4;

    float acc[4][24];
    #pragma unroll
    for (int i = 0; i < 4; ++i)
        #pragma unroll
        for (int j = 0; j < 24; ++j) acc[i][j] = 0.f;

    for (int s = 0; s < NSLAB; ++s) {
        // issue next slab's global loads before the barrier (latency hidden
        // behind this slab's FMAs; vmcnt waited only at the ds_write below)
        float2 nreg[3];
        if (s + 1 < NSLAB) {
            #pragma unroll
            for (int j = 0; j < 3; ++j) nreg[j] = w1v[(size_t)(s + 1) * 768 + tid + j * 256];
        }
        __syncthreads();   // Ws[s&1] writes visible; prior reads of Ws[(s+1)&1] done
        const float* Wb = Ws[s & 1];
        const float* Xrow = &Xs[r0 * XPAD + s * KB];
        #pragma unroll
        for (int kk = 0; kk < KB; ++kk) {
            float a[4];
            #pragma unroll
            for (int i = 0; i < 4; ++i) a[i] = Xrow[i * XPAD + kk];
            float4 bv[6];
            const float* wrow = &Wb[kk * HID2];
            #pragma unroll
            for (int m = 0; m < 6; ++m) bv[m] = *(const float4*)(&wrow[m * 64 + cg * 4]);
            #pragma unroll
            for (int i = 0; i < 4; ++i) {
                #pragma unroll
                for (int m = 0; m < 6; ++m) {
                    acc[i][m*4+0] = fmaf(a[i], bv[m].x, acc[i][m*4+0]);
                    acc[i][m*4+1] = fmaf(a[i], bv[m].y, acc[i][m*4+1]);
                    acc[i][m*4+2] = fmaf(a[i], bv[m].z, acc[i][m*4+2]);
                    acc[i][m*4+3] = fmaf(a[i], bv[m].w, acc[i][m*4+3]);
                }
            }
        }
        if (s + 1 < NSLAB) {
            float2* dst = (float2*)Ws[(s + 1) & 1];
            #pragma unroll
            for (int j = 0; j < 3; ++j) dst[tid + j * 256] = nreg[j];
        }
    }

    // epilogue: +b1, LayerNorm over 384 (own 24 + shfl over the 16 col-groups),
    // ReLU, dot with W2, +b2
    float4 b1v[6], gav[6], bev[6], w2v[6];
    #pragma unroll
    for (int m = 0; m < 6; ++m) {
        int c0 = m * 64 + cg * 4;
        b1v[m] = *(const float4*)(&b1[c0]);
        gav[m] = *(const float4*)(&gamma[c0]);
        bev[m] = *(const float4*)(&beta[c0]);
        w2v[m] = *(const float4*)(&W2[c0]);
    }
    const float b2v = b2[0];

    #pragma unroll
    for (int i = 0; i < 4; ++i) {
        #pragma unroll
        for (int m = 0; m < 6; ++m) {
            acc[i][m*4+0] += b1v[m].x;
            acc[i][m*4+1] += b1v[m].y;
            acc[i][m*4+2] += b1v[m].z;
            acc[i][m*4+3] += b1v[m].w;
        }
    }

    #pragma unroll
    for (int i = 0; i < 4; ++i) {
        float s = 0.f, s2 = 0.f;
        #pragma unroll
        for (int j = 0; j < 24; ++j) { float v = acc[i][j]; s += v; s2 += v * v; }
        #pragma unroll
        for (int off = 1; off < 16; off <<= 1) {
            s  += __shfl_xor(s,  off);
            s2 += __shfl_xor(s2, off);
        }
        float mu  = s  * (1.f / HID2);
        float var = s2 * (1.f / HID2) - mu * mu;
        float rs  = rsqrtf(var + LNEPS);
        float lg = 0.f;
        #pragma unroll
        for (int m = 0; m < 6; ++m) {
            float zn;
            zn = (acc[i][m*4+0] - mu) * rs * gav[m].x + bev[m].x; zn = fmaxf(zn, 0.f); lg = fmaf(zn, w2v[m].x, lg);
            zn = (acc[i][m*4+1] - mu) * rs * gav[m].y + bev[m].y; zn = fmaxf(zn, 0.f); lg = fmaf(zn, w2v[m].y, lg);
            zn = (acc[i][m*4+2] - mu) * rs * gav[m].z + bev[m].z; zn = fmaxf(zn, 0.f); lg = fmaf(zn, w2v[m].z, lg);
            zn = (acc[i][m*4+3] - mu) * rs * gav[m].w + bev[m].w; zn = fmaxf(zn, 0.f); lg = fmaf(zn, w2v[m].w, lg);
        }
        #pragma unroll
        for (int off = 1; off < 16; off <<= 1) lg += __shfl_xor(lg, off);
        if (cg == 0) logits_out[row0 + r0 + i] = lg + b2v;
    }
}

// ---------------------------------------------------------------------------
// Kernel B: per-graph top-K keep via rank counting (stable, ties by lower
// index = jax.lax.top_k). Emits packed (keep, logit) float2; zeroes touched.
// ---------------------------------------------------------------------------
__global__ __launch_bounds__(256) void topk_kernel(
    const float* __restrict__ logits, float2* __restrict__ klog,
    int* __restrict__ touched)
{
    __shared__ float arr[NPG];
    const int tid = threadIdx.x;
    const int n = blockIdx.x * NPG + tid;
    float v = logits[n];
    arr[tid] = v;
    touched[n] = 0;
    __syncthreads();
    int rank = 0;
    #pragma unroll 16
    for (int j = 0; j < NPG; ++j) {
        float a = arr[j];
        rank += (a > v || (a == v && j < tid)) ? 1 : 0;
    }
    klog[n] = make_float2((rank < KTOP) ? 1.0f : 0.0f, v);
}

// ---------------------------------------------------------------------------
// Kernel C: edge mask + edge weight + touched marking.
// 4 edges/thread; packed float2 gathers; PLAIN stores to touched (only value
// ever written is 1 -> write-write races benign; kernel boundary publishes).
// ---------------------------------------------------------------------------
__global__ __launch_bounds__(256) void edge_kernel(
    const int* __restrict__ ei, const float2* __restrict__ klog,
    float4* __restrict__ mask_out, float4* __restrict__ w_out,
    int* __restrict__ touched)
{
    const int t = blockIdx.x * blockDim.x + threadIdx.x;   // [0, NE/4)
    const int4 s4 = ((const int4*)ei)[t];
    const int4 d4 = ((const int4*)(ei + NE))[t];

    float m[4], w[4];
    const int ss[4] = {s4.x, s4.y, s4.z, s4.w};
    const int dd[4] = {d4.x, d4.y, d4.z, d4.w};
    #pragma unroll
    for (int i = 0; i < 4; ++i) {
        float2 ks = klog[ss[i]];
        float2 kd = klog[dd[i]];
        float mm = ks.x * kd.x;
        m[i] = mm;
        w[i] = (ks.y + kd.y) * mm;
        if (mm != 0.f) {
            touched[ss[i]] = 1;
            touched[dd[i]] = 1;
        }
    }
    mask_out[t] = make_float4(m[0], m[1], m[2], m[3]);
    w_out[t]    = make_float4(w[0], w[1], w[2], w[3]);
}

// ---------------------------------------------------------------------------
// Kernel D: node mask from touched
// ---------------------------------------------------------------------------
__global__ __launch_bounds__(256) void nodemask_kernel(
    const int* __restrict__ touched, float* __restrict__ nm)
{
    const int n = blockIdx.x * blockDim.x + threadIdx.x;
    nm[n] = touched[n] ? 1.0f : 0.0f;
}

extern "C" void kernel_launch(void* const* d_in, const int* in_sizes, int n_in,
                              void* d_out, int out_size, void* d_ws, size_t ws_size,
                              hipStream_t stream)
{
    const float* h     = (const float*)d_in[0];
    const float* g     = (const float*)d_in[1];
    const int*   ei    = (const int*)d_in[2];
    const float* W1    = (const float*)d_in[3];
    const float* b1    = (const float*)d_in[4];
    const float* gamma = (const float*)d_in[5];
    const float* beta  = (const float*)d_in[6];
    const float* W2    = (const float*)d_in[7];
    const float* b2    = (const float*)d_in[8];

    float* out        = (float*)d_out;
    float* out_mask   = out;                       // [E]
    float* out_w      = out + (size_t)NE;          // [E]
    float* out_logits = out + 2 * (size_t)NE;      // [N]
    float* out_nm     = out_logits + (size_t)NN;   // [N]

    float2* klog   = (float2*)d_ws;                          // N float2 (2 MB)
    int*    touched = (int*)((char*)d_ws + (size_t)NN * 8);  // N ints (1 MB)

    hipLaunchKernelGGL(logits_kernel, dim3(NN / ROWS), dim3(256), 0, stream,
                       h, g, W1, b1, gamma, beta, W2, b2, out_logits);
    hipLaunchKernelGGL(topk_kernel, dim3(NB), dim3(256), 0, stream,
                       out_logits, klog, touched);
    hipLaunchKernelGGL(edge_kernel, dim3(NE / 1024), dim3(256), 0, stream,
                       ei, klog, (float4*)out_mask, (float4*)out_w, touched);
    hipLaunchKernelGGL(nodemask_kernel, dim3(NN / 256), dim3(256), 0, stream,
                       touched, out_nm);
}

// Round 3
// 812.548 us; speedup vs baseline: 1.4189x; 1.1925x over previous
//
#include <hip/hip_runtime.h>
#include <math.h>

#define NPG 256
#define NB 1024
#define NN (NB * NPG)          // 262144 nodes
#define HID 192
#define HID2 384
#define NE 4194304
#define KTOP 231
#define LNEPS 1e-5f

#define ROWS 64                // rows (nodes) per block
#define KC 4                   // k-chunk for W1 double-buffered staging
#define NCH (HID / KC)         // 48 chunks

// ---------------------------------------------------------------------------
// Kernel A: fused logits = Linear(192->384) -> LayerNorm -> ReLU -> Linear(384->1)
// Tiling flipped for W register reuse: lane -> 6 cols (col = lane + 64j),
// wave -> 16 rows. Per chunk each lane loads W once into 24 regs (stride-1
// ds_read_b32, conflict-free) and reuses across 16 rows; X is a wave-uniform
// ds_read_b128 broadcast. LDS traffic ~4x lower than col-tiled variant.
// ---------------------------------------------------------------------------
__global__ __launch_bounds__(256) void logits_kernel(
    const float* __restrict__ h, const float* __restrict__ g,
    const float* __restrict__ W1, const float* __restrict__ b1,
    const float* __restrict__ gamma, const float* __restrict__ beta,
    const float* __restrict__ W2, const float* __restrict__ b2,
    float* __restrict__ logits_out)
{
    __shared__ float Xs[ROWS * HID];        // 64*192*4 = 49152 B (no pad: broadcast reads)
    __shared__ float Ws[2][KC * HID2];      // 2*4*384*4 = 12288 B (tot 61440)

    const int tid  = threadIdx.x;
    const int lane = tid & 63;
    const int wav  = tid >> 6;              // 0..3
    const int row0 = blockIdx.x * ROWS;
    const int graph = row0 >> 8;            // row0 / NPG

    // stage X = h + g_rep (64 rows x 192 cols = 3072 float4, 12 per thread)
    {
        const float4* h4 = (const float4*)(h + (size_t)row0 * HID);
        const float4* g4 = (const float4*)(g + (size_t)graph * HID);
        #pragma unroll
        for (int it = 0; it < 12; ++it) {
            int f = tid + it * 256;
            int r = f / 48, c = f - r * 48;        // c in float4 units
            float4 hv = h4[r * 48 + c];
            float4 gv = g4[c];
            *(float4*)(&Xs[r * HID + c * 4]) =
                make_float4(hv.x + gv.x, hv.y + gv.y, hv.z + gv.z, hv.w + gv.w);
        }
    }

    // prologue: W chunk 0 -> registers -> Ws[0]  (chunk = 1536 floats = 768 float2)
    const float2* w1v = (const float2*)W1;
    {
        float2 wreg[3];
        #pragma unroll
        for (int j = 0; j < 3; ++j) wreg[j] = w1v[tid + j * 256];
        float2* dst = (float2*)Ws[0];
        #pragma unroll
        for (int j = 0; j < 3; ++j) dst[tid + j * 256] = wreg[j];
    }

    float acc[16][6];
    #pragma unroll
    for (int r = 0; r < 16; ++r)
        #pragma unroll
        for (int j = 0; j < 6; ++j) acc[r][j] = 0.f;

    for (int s = 0; s < NCH; ++s) {
        float2 nreg[3];
        if (s + 1 < NCH) {
            #pragma unroll
            for (int j = 0; j < 3; ++j) nreg[j] = w1v[(size_t)(s + 1) * 768 + tid + j * 256];
        }
        __syncthreads();
        const float* Wb = Ws[s & 1];
        float w[KC][6];
        #pragma unroll
        for (int kk = 0; kk < KC; ++kk)
            #pragma unroll
            for (int j = 0; j < 6; ++j) w[kk][j] = Wb[kk * HID2 + j * 64 + lane];
        const float* Xp = &Xs[(wav * 16) * HID + s * KC];
        #pragma unroll
        for (int r = 0; r < 16; ++r) {
            float4 x = *(const float4*)(Xp + r * HID);   // wave-uniform broadcast
            #pragma unroll
            for (int j = 0; j < 6; ++j) {
                acc[r][j] = fmaf(x.x, w[0][j], acc[r][j]);
                acc[r][j] = fmaf(x.y, w[1][j], acc[r][j]);
                acc[r][j] = fmaf(x.z, w[2][j], acc[r][j]);
                acc[r][j] = fmaf(x.w, w[3][j], acc[r][j]);
            }
        }
        if (s + 1 < NCH) {
            float2* dst = (float2*)Ws[(s + 1) & 1];
            #pragma unroll
            for (int j = 0; j < 3; ++j) dst[tid + j * 256] = nreg[j];
        }
    }

    // epilogue: +b1, LayerNorm across the full wave (64 lanes x 6 cols), ReLU,
    // dot with W2, +b2. One full-wave shfl reduction per row.
    float b1v[6], gav[6], bev[6], w2v[6];
    #pragma unroll
    for (int j = 0; j < 6; ++j) {
        int c = j * 64 + lane;
        b1v[j] = b1[c]; gav[j] = gamma[c]; bev[j] = beta[c]; w2v[j] = W2[c];
    }
    const float b2v = b2[0];

    #pragma unroll
    for (int r = 0; r < 16; ++r) {
        float z[6];
        float s1 = 0.f, s2 = 0.f;
        #pragma unroll
        for (int j = 0; j < 6; ++j) {
            z[j] = acc[r][j] + b1v[j];
            s1 += z[j];
            s2 += z[j] * z[j];
        }
        #pragma unroll
        for (int off = 1; off < 64; off <<= 1) {
            s1 += __shfl_xor(s1, off);
            s2 += __shfl_xor(s2, off);
        }
        float mu  = s1 * (1.f / HID2);
        float var = s2 * (1.f / HID2) - mu * mu;
        float rs  = rsqrtf(var + LNEPS);
        float lg = 0.f;
        #pragma unroll
        for (int j = 0; j < 6; ++j) {
            float zn = (z[j] - mu) * rs * gav[j] + bev[j];
            zn = fmaxf(zn, 0.f);
            lg = fmaf(zn, w2v[j], lg);
        }
        #pragma unroll
        for (int off = 1; off < 64; off <<= 1) lg += __shfl_xor(lg, off);
        if (lane == 0) logits_out[row0 + wav * 16 + r] = lg + b2v;
    }
}

// ---------------------------------------------------------------------------
// Kernel B: per-graph top-K via rank counting (stable, ties by lower index =
// jax.lax.top_k). Emits kl[n] = kept ? logit : NaN (single 4B gather later).
// Also zeroes touched bytes.
// ---------------------------------------------------------------------------
__global__ __launch_bounds__(256) void topk_kernel(
    const float* __restrict__ logits, float* __restrict__ kl,
    unsigned char* __restrict__ touched)
{
    __shared__ float arr[NPG];
    const int tid = threadIdx.x;
    const int n = blockIdx.x * NPG + tid;
    float v = logits[n];
    arr[tid] = v;
    touched[n] = 0;
    __syncthreads();
    int rank = 0;
    #pragma unroll 16
    for (int j = 0; j < NPG; ++j) {
        float a = arr[j];
        rank += (a > v || (a == v && j < tid)) ? 1 : 0;
    }
    kl[n] = (rank < KTOP) ? v : __builtin_nanf("");
}

// ---------------------------------------------------------------------------
// Kernel C: edge mask + weight + touched marking. NaN-poisoned logits make
// mask = !isnan(ls+ld). Plain idempotent uchar stores to touched.
// ---------------------------------------------------------------------------
__global__ __launch_bounds__(256) void edge_kernel(
    const int* __restrict__ ei, const float* __restrict__ kl,
    float4* __restrict__ mask_out, float4* __restrict__ w_out,
    unsigned char* __restrict__ touched)
{
    const int t = blockIdx.x * blockDim.x + threadIdx.x;   // [0, NE/4)
    const int4 s4 = ((const int4*)ei)[t];
    const int4 d4 = ((const int4*)(ei + NE))[t];

    float m[4], w[4];
    const int ss[4] = {s4.x, s4.y, s4.z, s4.w};
    const int dd[4] = {d4.x, d4.y, d4.z, d4.w};
    #pragma unroll
    for (int i = 0; i < 4; ++i) {
        float ls = kl[ss[i]];
        float ld = kl[dd[i]];
        float sum = ls + ld;
        bool ok = (sum == sum);          // false if either endpoint dropped
        m[i] = ok ? 1.0f : 0.0f;
        w[i] = ok ? sum : 0.0f;
        if (ok) {
            touched[ss[i]] = 1;
            touched[dd[i]] = 1;
        }
    }
    mask_out[t] = make_float4(m[0], m[1], m[2], m[3]);
    w_out[t]    = make_float4(w[0], w[1], w[2], w[3]);
}

// ---------------------------------------------------------------------------
// Kernel D: node mask from touched bytes (4 nodes per thread)
// ---------------------------------------------------------------------------
__global__ __launch_bounds__(256) void nodemask_kernel(
    const uchar4* __restrict__ touched, float4* __restrict__ nm)
{
    const int t = blockIdx.x * blockDim.x + threadIdx.x;   // [0, NN/4)
    uchar4 tv = touched[t];
    nm[t] = make_float4(tv.x ? 1.f : 0.f, tv.y ? 1.f : 0.f,
                        tv.z ? 1.f : 0.f, tv.w ? 1.f : 0.f);
}

extern "C" void kernel_launch(void* const* d_in, const int* in_sizes, int n_in,
                              void* d_out, int out_size, void* d_ws, size_t ws_size,
                              hipStream_t stream)
{
    const float* h     = (const float*)d_in[0];
    const float* g     = (const float*)d_in[1];
    const int*   ei    = (const int*)d_in[2];
    const float* W1    = (const float*)d_in[3];
    const float* b1    = (const float*)d_in[4];
    const float* gamma = (const float*)d_in[5];
    const float* beta  = (const float*)d_in[6];
    const float* W2    = (const float*)d_in[7];
    const float* b2    = (const float*)d_in[8];

    float* out        = (float*)d_out;
    float* out_mask   = out;                       // [E]
    float* out_w      = out + (size_t)NE;          // [E]
    float* out_logits = out + 2 * (size_t)NE;      // [N]
    float* out_nm     = out_logits + (size_t)NN;   // [N]

    float*         kl      = (float*)d_ws;                           // N floats (1 MB)
    unsigned char* touched = (unsigned char*)((char*)d_ws + (size_t)NN * 4); // N bytes

    hipLaunchKernelGGL(logits_kernel, dim3(NN / ROWS), dim3(256), 0, stream,
                       h, g, W1, b1, gamma, beta, W2, b2, out_logits);
    hipLaunchKernelGGL(topk_kernel, dim3(NB), dim3(256), 0, stream,
                       out_logits, kl, touched);
    hipLaunchKernelGGL(edge_kernel, dim3(NE / 1024), dim3(256), 0, stream,
                       ei, kl, (float4*)out_mask, (float4*)out_w, touched);
    hipLaunchKernelGGL(nodemask_kernel, dim3(NN / 1024), dim3(256), 0, stream,
                       (const uchar4*)touched, (float4*)out_nm);
}